// Round 2
// baseline (1103.965 us; speedup 1.0000x reference)
//
#include <hip/hip_runtime.h>
#include <hip/hip_bf16.h>

#define NV    512           // N nodes
#define BN    1024          // B*N rows
#define NNB   30            // neighbors
#define DIM   64
#define HEADS 8
#define DH    128
#define INNER 1024          // HEADS*DH

// jax.nn.gelu default: approximate=True (tanh form)
__device__ __forceinline__ float gelu_t(float x){
    float x3 = x*x*x;
    return 0.5f*x*(1.0f + tanhf(0.7978845608028654f*(x + 0.044715f*x3)));
}

// ---------------------------------------------------------------- embed
// x = [sin(feats), cos(feats)] (6), h = relu(x @ fe_w + fe_b) (64)
// also copy coors into f32 working buffer A
__global__ __launch_bounds__(64) void k_embed(const float* __restrict__ feats,
                                              const float* __restrict__ coors,
                                              const float* __restrict__ fe_w,
                                              const float* __restrict__ fe_b,
                                              float* __restrict__ h,
                                              float* __restrict__ coorsA){
    int row = blockIdx.x;            // b*N + i
    int t = threadIdx.x;             // 0..63
    __shared__ float x[6];
    if (t < 3){
        float f = feats[row*3+t];
        x[t]   = sinf(f);
        x[t+3] = cosf(f);
        coorsA[row*3+t] = coors[row*3+t];
    }
    __syncthreads();
    float acc = fe_b[t];
    #pragma unroll
    for (int k = 0; k < 6; k++) acc += x[k]*fe_w[k*DIM+t];
    h[row*DIM+t] = fmaxf(acc, 0.0f);
}

// ---------------------------------------------------------------- LN1 + qkv
__global__ __launch_bounds__(256) void k_ln_qkv(const float* __restrict__ h,
                                                const float* __restrict__ g,
                                                const float* __restrict__ be,
                                                const float* __restrict__ w,   // (64,3072)
                                                float* __restrict__ qkv){
    int row = blockIdx.x;
    int t = threadIdx.x;
    __shared__ float xn[DIM];
    if (t < 64){
        float v = h[row*DIM+t];
        float s = v;
        #pragma unroll
        for (int m = 32; m >= 1; m >>= 1) s += __shfl_xor(s, m, 64);
        float mu = s * (1.0f/64.0f);
        float d  = v - mu;
        float vv = d*d;
        #pragma unroll
        for (int m = 32; m >= 1; m >>= 1) vv += __shfl_xor(vv, m, 64);
        float var = vv * (1.0f/64.0f);
        xn[t] = d / sqrtf(var + 1e-5f) * g[t] + be[t];
    }
    __syncthreads();
    for (int o = t; o < 3*INNER; o += 256){
        float acc = 0.0f;
        #pragma unroll 8
        for (int k = 0; k < DIM; k++) acc += xn[k]*w[k*(3*INNER)+o];
        qkv[(size_t)row*(3*INNER) + o] = acc;
    }
}

// ---------------------------------------------------------------- top-k 30
__global__ __launch_bounds__(256) void k_topk(const float* __restrict__ coors,
                                              int* __restrict__ idx){
    int row = blockIdx.x;
    int b = row >> 9;
    int t = threadIdx.x;
    __shared__ float d2[NV];
    __shared__ float rv[256];
    __shared__ int   ri[256];
    float cx = coors[row*3+0], cy = coors[row*3+1], cz = coors[row*3+2];
    for (int j = t; j < NV; j += 256){
        const float* cj = &coors[(size_t)(b*NV+j)*3];
        float dx = cx - cj[0], dy = cy - cj[1], dz = cz - cj[2];
        d2[j] = dx*dx + dy*dy + dz*dz;
    }
    __syncthreads();
    for (int sel = 0; sel < NNB; sel++){
        float bv = 1e30f; int bi = NV;
        for (int j = t; j < NV; j += 256){
            float v = d2[j];
            if (v < bv || (v == bv && j < bi)){ bv = v; bi = j; }
        }
        rv[t] = bv; ri[t] = bi;
        __syncthreads();
        for (int s = 128; s >= 1; s >>= 1){
            if (t < s){
                float v2 = rv[t+s]; int i2 = ri[t+s];
                if (v2 < rv[t] || (v2 == rv[t] && i2 < ri[t])){ rv[t] = v2; ri[t] = i2; }
            }
            __syncthreads();
        }
        if (t == 0){ idx[row*NNB+sel] = ri[0]; d2[ri[0]] = 1e30f; }
        __syncthreads();
    }
}

// ---------------------------------------------------------------- fused attention layer core
__global__ __launch_bounds__(256) void k_attn(const float* __restrict__ qkv,
                                              const int*   __restrict__ idx,
                                              const float* __restrict__ cin,
                                              float*       __restrict__ cout,
                                              const float* __restrict__ edges,
                                              float*       __restrict__ h,
                                              const float* __restrict__ ew1, const float* __restrict__ eb1,
                                              const float* __restrict__ ew2, const float* __restrict__ eb2,
                                              const float* __restrict__ cw1, const float* __restrict__ cb1,
                                              const float* __restrict__ cw2, const float* __restrict__ cb2,
                                              const float* __restrict__ c_scale, const float* __restrict__ c_comb,
                                              const float* __restrict__ out_w,  const float* __restrict__ out_b){
    int row = blockIdx.x;
    int b = row >> 9, i = row & (NV-1);
    int t = threadIdx.x;

    __shared__ float q[INNER];        // later reused as "out"
    __shared__ float qk[NNB][HEADS];  // logits, later overwritten by edge-MLP output
    __shared__ float t18[NNB][18];
    __shared__ float t64s[NNB][64];
    __shared__ float cwh[NNB][HEADS];
    __shared__ float attn[NNB][HEADS];
    __shared__ float ej[NNB];
    __shared__ float reln[NNB][3];
    __shared__ float wj[NNB];
    __shared__ int   jid[NNB];
    __shared__ float red[256];

    for (int o = t; o < INNER; o += 256) q[o] = qkv[(size_t)row*(3*INNER) + o];
    if (t < NNB) jid[t] = idx[row*NNB + t];
    __syncthreads();

    // ---- pass 1: qk logits (wave-per-neighbor), plus edge/rel loads
    int wave = t >> 6, lane = t & 63;
    for (int j = wave; j < NNB; j += 4){
        int jj = jid[j];
        const float* krow = &qkv[(size_t)(b*NV+jj)*(3*INNER) + INNER];
        int hh = lane >> 3, part = lane & 7;
        const float* ks = krow + hh*DH + part*16;
        const float* qs = &q[hh*DH + part*16];
        float acc = 0.0f;
        #pragma unroll
        for (int e = 0; e < 16; e++) acc += qs[e]*ks[e];
        acc += __shfl_xor(acc, 1, 64);
        acc += __shfl_xor(acc, 2, 64);
        acc += __shfl_xor(acc, 4, 64);
        if (part == 0) qk[j][hh] = acc * 0.08838834764831845f;  // 1/sqrt(128)
    }
    if (t < NNB){
        int jj = jid[t];
        ej[t] = edges[(size_t)(b*NV+i)*NV + jj];
        float rx = cin[(b*NV+i)*3+0] - cin[(b*NV+jj)*3+0];
        float ry = cin[(b*NV+i)*3+1] - cin[(b*NV+jj)*3+1];
        float rz = cin[(b*NV+i)*3+2] - cin[(b*NV+jj)*3+2];
        float s = rx*rx + ry*ry + rz*rz;
        float den = fmaxf(sqrtf(s == 0.0f ? 1.0f : s), 1e-8f);
        float cs = c_scale[0];
        reln[t][0] = rx/den*cs;
        reln[t][1] = ry/den*cs;
        reln[t][2] = rz/den*cs;
    }
    __syncthreads();

    // ---- edge MLP layer 1: (qk||e) (9) -> 18, gelu
    for (int id = t; id < NNB*18; id += 256){
        int j = id/18, u = id%18;
        float acc = eb1[u];
        #pragma unroll
        for (int k = 0; k < 8; k++) acc += qk[j][k]*ew1[k*18+u];
        acc += ej[j]*ew1[8*18+u];
        t18[j][u] = gelu_t(acc);
    }
    __syncthreads();
    // ---- edge MLP layer 2: 18 -> 8 (overwrites qk with conditioned logits)
    if (t < NNB*HEADS){
        int j = t/HEADS, hh = t%HEADS;
        float acc = eb2[hh];
        #pragma unroll
        for (int k = 0; k < 18; k++) acc += t18[j][k]*ew2[k*HEADS+hh];
        red[t] = acc;          // staging to avoid rw hazard on qk
    }
    __syncthreads();
    if (t < NNB*HEADS) qk[t/HEADS][t%HEADS] = red[t];
    __syncthreads();

    // ---- coord MLP: gelu(qk) (8) -> 64 gelu -> 8
    for (int id = t; id < NNB*64; id += 256){
        int j = id/64, u = id%64;
        float acc = cb1[u];
        #pragma unroll
        for (int k = 0; k < 8; k++) acc += gelu_t(qk[j][k])*cw1[k*64+u];
        t64s[j][u] = gelu_t(acc);
    }
    __syncthreads();
    if (t < NNB*HEADS){
        int j = t/HEADS, hh = t%HEADS;
        float acc = cb2[hh];
        #pragma unroll 8
        for (int k = 0; k < 64; k++) acc += t64s[j][k]*cw2[k*HEADS+hh];
        cwh[j][hh] = acc;
    }
    __syncthreads();

    // ---- per-neighbor coord weight, per-head softmax
    if (t < NNB){
        float acc = 0.0f;
        #pragma unroll
        for (int hh = 0; hh < HEADS; hh++) acc += cwh[t][hh]*c_comb[hh];
        wj[t] = acc;
    }
    if (t >= 64 && t < 64+HEADS){
        int hh = t - 64;
        float m = -1e30f;
        for (int j = 0; j < NNB; j++) m = fmaxf(m, qk[j][hh]);
        float l = 0.0f;
        for (int j = 0; j < NNB; j++){ float p = expf(qk[j][hh]-m); attn[j][hh] = p; l += p; }
        float rl = 1.0f/l;
        for (int j = 0; j < NNB; j++) attn[j][hh] *= rl;
    }
    __syncthreads();

    // ---- coordinate update
    if (t < 3){
        float acc = 0.0f;
        for (int j = 0; j < NNB; j++) acc += wj[j]*reln[j][t];
        cout[(b*NV+i)*3+t] = cin[(b*NV+i)*3+t] + acc;
    }

    // ---- attn @ V  (reuse q[] as out accumulator; last q read was pass 1)
    for (int o = t; o < INNER; o += 256){
        int hh = o >> 7;
        float acc = 0.0f;
        for (int j = 0; j < NNB; j++)
            acc += attn[j][hh]*qkv[(size_t)(b*NV+jid[j])*(3*INNER) + 2*INNER + o];
        q[o] = acc;
    }
    __syncthreads();

    // ---- out @ out_w (1024 -> 64) + residual
    int d = t & 63, part = t >> 6;
    float acc = 0.0f;
    for (int o = part*256; o < part*256+256; o++)
        acc += q[o]*out_w[o*DIM+d];
    red[t] = acc;
    __syncthreads();
    if (t < 64){
        float r = red[t] + red[t+64] + red[t+128] + red[t+192];
        h[row*DIM+t] += r + out_b[t];
    }
}

// ---------------------------------------------------------------- LN2 + FFN
__global__ __launch_bounds__(256) void k_ffn(float* __restrict__ h,
                                             const float* __restrict__ g,
                                             const float* __restrict__ be,
                                             const float* __restrict__ fw1, const float* __restrict__ fb1,
                                             const float* __restrict__ fw2, const float* __restrict__ fb2){
    int row = blockIdx.x;
    int t = threadIdx.x;
    __shared__ float y[DIM];
    __shared__ float u[256];
    if (t < 64){
        float v = h[row*DIM+t];
        float s = v;
        #pragma unroll
        for (int m = 32; m >= 1; m >>= 1) s += __shfl_xor(s, m, 64);
        float mu = s * (1.0f/64.0f);
        float dd = v - mu;
        float vv = dd*dd;
        #pragma unroll
        for (int m = 32; m >= 1; m >>= 1) vv += __shfl_xor(vv, m, 64);
        float var = vv * (1.0f/64.0f);
        y[t] = dd / sqrtf(var + 1e-5f) * g[t] + be[t];
    }
    __syncthreads();
    {
        float acc = fb1[t];
        #pragma unroll 8
        for (int k = 0; k < 64; k++) acc += y[k]*fw1[k*256+t];
        u[t] = gelu_t(acc);
    }
    __syncthreads();
    if (t < 64){
        float acc = fb2[t];
        #pragma unroll 8
        for (int k = 0; k < 256; k++) acc += u[k]*fw2[k*DIM+t];
        h[row*DIM+t] += acc;
    }
}

// ---------------------------------------------------------------- classifier + softmax
__global__ __launch_bounds__(64) void k_cls(const float* __restrict__ h,
                                            const float* __restrict__ cls_w,
                                            const float* __restrict__ cls_b,
                                            float* __restrict__ out){
    int row = blockIdx.x;
    int t = threadIdx.x;
    __shared__ float lg[20];
    if (t < 20){
        float acc = cls_b[t];
        #pragma unroll 8
        for (int k = 0; k < 64; k++) acc += h[row*DIM+k]*cls_w[k*20+t];
        lg[t] = acc;
    }
    __syncthreads();
    if (t < 20){
        float m = -1e30f;
        for (int c = 0; c < 20; c++) m = fmaxf(m, lg[c]);
        float l = 0.0f;
        for (int c = 0; c < 20; c++) l += expf(lg[c]-m);
        out[row*20+t] = expf(lg[t]-m)/l;
    }
}

extern "C" void kernel_launch(void* const* d_in, const int* in_sizes, int n_in,
                              void* d_out, int out_size, void* d_ws, size_t ws_size,
                              hipStream_t stream) {
    const float* feats = (const float*)d_in[0];
    const float* coors = (const float*)d_in[1];
    const float* edges = (const float*)d_in[2];
    // d_in[3] = mask (all true) — unused
    const float* fe_w  = (const float*)d_in[4];
    const float* fe_b  = (const float*)d_in[5];
    const float* ln1_g = (const float*)d_in[6];
    const float* ln1_b = (const float*)d_in[7];
    const float* qkv_w = (const float*)d_in[8];
    const float* out_w = (const float*)d_in[9];
    const float* out_b = (const float*)d_in[10];
    const float* ew1   = (const float*)d_in[11];
    const float* eb1   = (const float*)d_in[12];
    const float* ew2   = (const float*)d_in[13];
    const float* eb2   = (const float*)d_in[14];
    const float* cw1   = (const float*)d_in[15];
    const float* cb1   = (const float*)d_in[16];
    const float* cw2   = (const float*)d_in[17];
    const float* cb2   = (const float*)d_in[18];
    const float* c_scale = (const float*)d_in[19];
    const float* c_comb  = (const float*)d_in[20];
    const float* ln2_g = (const float*)d_in[21];
    const float* ln2_b = (const float*)d_in[22];
    const float* fw1   = (const float*)d_in[23];
    const float* fb1   = (const float*)d_in[24];
    const float* fw2   = (const float*)d_in[25];
    const float* fb2   = (const float*)d_in[26];
    const float* cls_w = (const float*)d_in[27];
    const float* cls_b = (const float*)d_in[28];

    float* ws   = (float*)d_ws;
    float* h    = ws;                       // 1024*64
    float* cA   = h + BN*DIM;               // 1024*3
    float* cB   = cA + BN*3;                // 1024*3
    float* qkv  = cB + BN*3;                // 1024*3072 (f32, ~12 MB)
    int*   idx  = (int*)(qkv + (size_t)BN*3*INNER); // 1024*30

    k_embed<<<BN, 64, 0, stream>>>(feats, coors, fe_w, fe_b, h, cA);

    float* cin = cA; float* cout = cB;
    for (int l = 0; l < 8; l++){
        k_ln_qkv<<<BN, 256, 0, stream>>>(h, ln1_g + l*DIM, ln1_b + l*DIM,
                                         qkv_w + (size_t)l*DIM*3*INNER, qkv);
        k_topk<<<BN, 256, 0, stream>>>(cin, idx);
        k_attn<<<BN, 256, 0, stream>>>(qkv, idx, cin, cout, edges, h,
                                       ew1 + l*9*18,  eb1 + l*18,
                                       ew2 + l*18*8,  eb2 + l*8,
                                       cw1 + l*8*64,  cb1 + l*64,
                                       cw2 + l*64*8,  cb2 + l*8,
                                       c_scale + l,   c_comb + l*8,
                                       out_w + (size_t)l*INNER*DIM, out_b + l*DIM);
        k_ffn<<<BN, 256, 0, stream>>>(h, ln2_g + l*DIM, ln2_b + l*DIM,
                                      fw1 + (size_t)l*DIM*256, fb1 + l*256,
                                      fw2 + (size_t)l*256*DIM, fb2 + l*64);
        float* tmp = cin; cin = cout; cout = tmp;
    }

    k_cls<<<BN, 64, 0, stream>>>(h, cls_w, cls_b, (float*)d_out);
}

// Round 3
// 736.963 us; speedup vs baseline: 1.4980x; 1.4980x over previous
//
#include <hip/hip_runtime.h>
#include <hip/hip_bf16.h>

#define NV    512           // N nodes
#define BN    1024          // B*N rows
#define NNB   30            // neighbors
#define DIM   64
#define HEADS 8
#define DH    128
#define INNER 1024          // HEADS*DH

// jax.nn.gelu default: approximate=True (tanh form)
__device__ __forceinline__ float gelu_t(float x){
    float x3 = x*x*x;
    return 0.5f*x*(1.0f + tanhf(0.7978845608028654f*(x + 0.044715f*x3)));
}

// ---------------------------------------------------------------- embed
__global__ __launch_bounds__(64) void k_embed(const float* __restrict__ feats,
                                              const float* __restrict__ coors,
                                              const float* __restrict__ fe_w,
                                              const float* __restrict__ fe_b,
                                              float* __restrict__ h,
                                              float* __restrict__ coorsA){
    int row = blockIdx.x;            // b*N + i
    int t = threadIdx.x;             // 0..63
    __shared__ float x[6];
    if (t < 3){
        float f = feats[row*3+t];
        x[t]   = sinf(f);
        x[t+3] = cosf(f);
        coorsA[row*3+t] = coors[row*3+t];
    }
    __syncthreads();
    float acc = fe_b[t];
    #pragma unroll
    for (int k = 0; k < 6; k++) acc += x[k]*fe_w[k*DIM+t];
    h[row*DIM+t] = fmaxf(acc, 0.0f);
}

// ---------------------------------------------------------------- LN1 + qkv as tiled GEMM
// grid: 16 row-tiles x 24 col-tiles; block 256.
// Each block: 64 rows (LN'd in-flight) x 128 cols of the (1024x64)@(64x3072) GEMM.
__global__ __launch_bounds__(256) void k_qkv(const float* __restrict__ h,
                                             const float* __restrict__ g,
                                             const float* __restrict__ be,
                                             const float* __restrict__ w,   // (64,3072)
                                             float* __restrict__ qkv){
    __shared__ float At[64][68];     // transposed LN'd activations: At[k][r]
    __shared__ float Wt[64][132];    // weight tile: Wt[k][c]
    int t  = threadIdx.x;
    int rt = blockIdx.x / 24, ct = blockIdx.x % 24;
    int row0 = rt*64, col0 = ct*128;
    int wv = t >> 6, lane = t & 63;

    // stage A with fused LayerNorm: each wave LNs 16 rows (lane = feature dim)
    float gk = g[lane], bk = be[lane];
    #pragma unroll 4
    for (int rr = 0; rr < 16; rr++){
        int r = wv*16 + rr;
        float v = h[(row0+r)*DIM + lane];
        float s = v;
        #pragma unroll
        for (int m = 32; m >= 1; m >>= 1) s += __shfl_xor(s, m, 64);
        float mu = s*(1.0f/64.0f);
        float d = v - mu;
        float vv = d*d;
        #pragma unroll
        for (int m = 32; m >= 1; m >>= 1) vv += __shfl_xor(vv, m, 64);
        At[lane][r] = d / sqrtf(vv*(1.0f/64.0f) + 1e-5f) * gk + bk;
    }
    // stage W tile (64 x 128), coalesced float4
    const float* wg = w + col0;
    #pragma unroll
    for (int i = t*4; i < 64*128; i += 1024){
        int k = i >> 7, c = i & 127;
        *(float4*)&Wt[k][c] = *(const float4*)&wg[k*3072 + c];
    }
    __syncthreads();

    // register-blocked 4 rows x 8 cols per thread (cols split 2x4 spaced 64 apart)
    int ty = t >> 4, tx = t & 15;
    float acc[4][8];
    #pragma unroll
    for (int i = 0; i < 4; i++)
        #pragma unroll
        for (int j = 0; j < 8; j++) acc[i][j] = 0.0f;

    #pragma unroll 2
    for (int k = 0; k < 64; k++){
        float4 a  = *(const float4*)&At[k][ty*4];
        float4 w0 = *(const float4*)&Wt[k][tx*4];
        float4 w1 = *(const float4*)&Wt[k][64 + tx*4];
        float av[4]  = {a.x, a.y, a.z, a.w};
        float wv8[8] = {w0.x, w0.y, w0.z, w0.w, w1.x, w1.y, w1.z, w1.w};
        #pragma unroll
        for (int i = 0; i < 4; i++)
            #pragma unroll
            for (int j = 0; j < 8; j++) acc[i][j] += av[i]*wv8[j];
    }

    #pragma unroll
    for (int i = 0; i < 4; i++){
        int r = row0 + ty*4 + i;
        float* dst = &qkv[(size_t)r*(3*INNER) + col0];
        *(float4*)&dst[tx*4]      = make_float4(acc[i][0], acc[i][1], acc[i][2], acc[i][3]);
        *(float4*)&dst[64 + tx*4] = make_float4(acc[i][4], acc[i][5], acc[i][6], acc[i][7]);
    }
}

// ---------------------------------------------------------------- top-k 30, one wave per row
__global__ __launch_bounds__(256) void k_topk(const float* __restrict__ coors,
                                              int* __restrict__ idx){
    int t = threadIdx.x;
    int wv = t >> 6, lane = t & 63;
    int row = blockIdx.x*4 + wv;
    int b = row >> 9;
    const float* cbp = coors + (size_t)b*NV*3;
    float cx = coors[row*3+0], cy = coors[row*3+1], cz = coors[row*3+2];
    float d2[8];
    int jb = lane*8;
    #pragma unroll
    for (int u = 0; u < 8; u++){
        float dx = cx - cbp[(jb+u)*3+0];
        float dy = cy - cbp[(jb+u)*3+1];
        float dz = cz - cbp[(jb+u)*3+2];
        d2[u] = dx*dx + dy*dy + dz*dz;
    }
    for (int sel = 0; sel < NNB; sel++){
        // local argmin (strict < keeps lowest index on ties)
        float bv = d2[0]; int bu = 0;
        #pragma unroll
        for (int u = 1; u < 8; u++) if (d2[u] < bv){ bv = d2[u]; bu = u; }
        int bj = jb + bu;
        // wave butterfly argmin, tie -> lower j (matches stable top_k)
        #pragma unroll
        for (int m = 32; m >= 1; m >>= 1){
            float ov = __shfl_xor(bv, m, 64);
            int   oj = __shfl_xor(bj, m, 64);
            if (ov < bv || (ov == bv && oj < bj)){ bv = ov; bj = oj; }
        }
        if (lane == 0) idx[row*NNB + sel] = bj;
        // owner invalidates (static-unrolled compare; no dynamic reg-array index)
        #pragma unroll
        for (int u = 0; u < 8; u++) if (jb + u == bj) d2[u] = 1e30f;
    }
}

// ---------------------------------------------------------------- fused attention layer core
__global__ __launch_bounds__(256) void k_attn(const float* __restrict__ qkv,
                                              const int*   __restrict__ idx,
                                              const float* __restrict__ cin,
                                              float*       __restrict__ cout,
                                              const float* __restrict__ edges,
                                              float*       __restrict__ h,
                                              const float* __restrict__ ew1, const float* __restrict__ eb1,
                                              const float* __restrict__ ew2, const float* __restrict__ eb2,
                                              const float* __restrict__ cw1, const float* __restrict__ cb1,
                                              const float* __restrict__ cw2, const float* __restrict__ cb2,
                                              const float* __restrict__ c_scale, const float* __restrict__ c_comb,
                                              const float* __restrict__ out_w,  const float* __restrict__ out_b){
    int row = blockIdx.x;
    int b = row >> 9, i = row & (NV-1);
    int t = threadIdx.x;

    __shared__ float q[INNER];        // later reused as "out"
    __shared__ float qk[NNB][HEADS];  // logits, later overwritten by edge-MLP output
    __shared__ float t18[NNB][18];
    __shared__ float t64s[NNB][64];
    __shared__ float cwh[NNB][HEADS];
    __shared__ float attn[NNB][HEADS];
    __shared__ float ej[NNB];
    __shared__ float reln[NNB][3];
    __shared__ float wj[NNB];
    __shared__ int   jid[NNB];
    __shared__ float red[256];

    for (int o = t; o < INNER; o += 256) q[o] = qkv[(size_t)row*(3*INNER) + o];
    if (t < NNB) jid[t] = idx[row*NNB + t];
    __syncthreads();

    // ---- pass 1: qk logits (wave-per-neighbor)
    int wave = t >> 6, lane = t & 63;
    for (int j = wave; j < NNB; j += 4){
        int jj = jid[j];
        const float* krow = &qkv[(size_t)(b*NV+jj)*(3*INNER) + INNER];
        int hh = lane >> 3, part = lane & 7;
        const float* ks = krow + hh*DH + part*16;
        const float* qs = &q[hh*DH + part*16];
        float acc = 0.0f;
        #pragma unroll
        for (int e = 0; e < 16; e++) acc += qs[e]*ks[e];
        acc += __shfl_xor(acc, 1, 64);
        acc += __shfl_xor(acc, 2, 64);
        acc += __shfl_xor(acc, 4, 64);
        if (part == 0) qk[j][hh] = acc * 0.08838834764831845f;  // 1/sqrt(128)
    }
    if (t < NNB){
        int jj = jid[t];
        ej[t] = edges[(size_t)(b*NV+i)*NV + jj];
        float rx = cin[(b*NV+i)*3+0] - cin[(b*NV+jj)*3+0];
        float ry = cin[(b*NV+i)*3+1] - cin[(b*NV+jj)*3+1];
        float rz = cin[(b*NV+i)*3+2] - cin[(b*NV+jj)*3+2];
        float s = rx*rx + ry*ry + rz*rz;
        float den = fmaxf(sqrtf(s == 0.0f ? 1.0f : s), 1e-8f);
        float cs = c_scale[0];
        reln[t][0] = rx/den*cs;
        reln[t][1] = ry/den*cs;
        reln[t][2] = rz/den*cs;
    }
    __syncthreads();

    // ---- edge MLP layer 1: (qk||e) (9) -> 18, gelu
    for (int id = t; id < NNB*18; id += 256){
        int j = id/18, u = id%18;
        float acc = eb1[u];
        #pragma unroll
        for (int k = 0; k < 8; k++) acc += qk[j][k]*ew1[k*18+u];
        acc += ej[j]*ew1[8*18+u];
        t18[j][u] = gelu_t(acc);
    }
    __syncthreads();
    // ---- edge MLP layer 2: 18 -> 8 (overwrites qk with conditioned logits)
    if (t < NNB*HEADS){
        int j = t/HEADS, hh = t%HEADS;
        float acc = eb2[hh];
        #pragma unroll
        for (int k = 0; k < 18; k++) acc += t18[j][k]*ew2[k*HEADS+hh];
        red[t] = acc;          // staging to avoid rw hazard on qk
    }
    __syncthreads();
    if (t < NNB*HEADS) qk[t/HEADS][t%HEADS] = red[t];
    __syncthreads();

    // ---- coord MLP: gelu(qk) (8) -> 64 gelu -> 8
    for (int id = t; id < NNB*64; id += 256){
        int j = id/64, u = id%64;
        float acc = cb1[u];
        #pragma unroll
        for (int k = 0; k < 8; k++) acc += gelu_t(qk[j][k])*cw1[k*64+u];
        t64s[j][u] = gelu_t(acc);
    }
    __syncthreads();
    if (t < NNB*HEADS){
        int j = t/HEADS, hh = t%HEADS;
        float acc = cb2[hh];
        #pragma unroll 8
        for (int k = 0; k < 64; k++) acc += t64s[j][k]*cw2[k*HEADS+hh];
        cwh[j][hh] = acc;
    }
    __syncthreads();

    // ---- per-neighbor coord weight, per-head softmax
    if (t < NNB){
        float acc = 0.0f;
        #pragma unroll
        for (int hh = 0; hh < HEADS; hh++) acc += cwh[t][hh]*c_comb[hh];
        wj[t] = acc;
    }
    if (t >= 64 && t < 64+HEADS){
        int hh = t - 64;
        float m = -1e30f;
        for (int j = 0; j < NNB; j++) m = fmaxf(m, qk[j][hh]);
        float l = 0.0f;
        for (int j = 0; j < NNB; j++){ float p = expf(qk[j][hh]-m); attn[j][hh] = p; l += p; }
        float rl = 1.0f/l;
        for (int j = 0; j < NNB; j++) attn[j][hh] *= rl;
    }
    __syncthreads();

    // ---- coordinate update
    if (t < 3){
        float acc = 0.0f;
        for (int j = 0; j < NNB; j++) acc += wj[j]*reln[j][t];
        cout[(b*NV+i)*3+t] = cin[(b*NV+i)*3+t] + acc;
    }

    // ---- attn @ V  (reuse q[] as out accumulator; last q read was pass 1)
    for (int o = t; o < INNER; o += 256){
        int hh = o >> 7;
        float acc = 0.0f;
        for (int j = 0; j < NNB; j++)
            acc += attn[j][hh]*qkv[(size_t)(b*NV+jid[j])*(3*INNER) + 2*INNER + o];
        q[o] = acc;
    }
    __syncthreads();

    // ---- out @ out_w (1024 -> 64) + residual
    int d = t & 63, part = t >> 6;
    float acc = 0.0f;
    for (int o = part*256; o < part*256+256; o++)
        acc += q[o]*out_w[o*DIM+d];
    red[t] = acc;
    __syncthreads();
    if (t < 64){
        float r = red[t] + red[t+64] + red[t+128] + red[t+192];
        h[row*DIM+t] += r + out_b[t];
    }
}

// ---------------------------------------------------------------- LN2 + FFN
__global__ __launch_bounds__(256) void k_ffn(float* __restrict__ h,
                                             const float* __restrict__ g,
                                             const float* __restrict__ be,
                                             const float* __restrict__ fw1, const float* __restrict__ fb1,
                                             const float* __restrict__ fw2, const float* __restrict__ fb2){
    int row = blockIdx.x;
    int t = threadIdx.x;
    __shared__ float y[DIM];
    __shared__ float u[256];
    if (t < 64){
        float v = h[row*DIM+t];
        float s = v;
        #pragma unroll
        for (int m = 32; m >= 1; m >>= 1) s += __shfl_xor(s, m, 64);
        float mu = s * (1.0f/64.0f);
        float dd = v - mu;
        float vv = dd*dd;
        #pragma unroll
        for (int m = 32; m >= 1; m >>= 1) vv += __shfl_xor(vv, m, 64);
        float var = vv * (1.0f/64.0f);
        y[t] = dd / sqrtf(var + 1e-5f) * g[t] + be[t];
    }
    __syncthreads();
    {
        float acc = fb1[t];
        #pragma unroll 8
        for (int k = 0; k < 64; k++) acc += y[k]*fw1[k*256+t];
        u[t] = gelu_t(acc);
    }
    __syncthreads();
    if (t < 64){
        float acc = fb2[t];
        #pragma unroll 8
        for (int k = 0; k < 256; k++) acc += u[k]*fw2[k*DIM+t];
        h[row*DIM+t] += acc;
    }
}

// ---------------------------------------------------------------- classifier + softmax
__global__ __launch_bounds__(64) void k_cls(const float* __restrict__ h,
                                            const float* __restrict__ cls_w,
                                            const float* __restrict__ cls_b,
                                            float* __restrict__ out){
    int row = blockIdx.x;
    int t = threadIdx.x;
    __shared__ float lg[20];
    if (t < 20){
        float acc = cls_b[t];
        #pragma unroll 8
        for (int k = 0; k < 64; k++) acc += h[row*DIM+k]*cls_w[k*20+t];
        lg[t] = acc;
    }
    __syncthreads();
    if (t < 20){
        float m = -1e30f;
        for (int c = 0; c < 20; c++) m = fmaxf(m, lg[c]);
        float l = 0.0f;
        for (int c = 0; c < 20; c++) l += expf(lg[c]-m);
        out[row*20+t] = expf(lg[t]-m)/l;
    }
}

extern "C" void kernel_launch(void* const* d_in, const int* in_sizes, int n_in,
                              void* d_out, int out_size, void* d_ws, size_t ws_size,
                              hipStream_t stream) {
    const float* feats = (const float*)d_in[0];
    const float* coors = (const float*)d_in[1];
    const float* edges = (const float*)d_in[2];
    // d_in[3] = mask (all true) — unused
    const float* fe_w  = (const float*)d_in[4];
    const float* fe_b  = (const float*)d_in[5];
    const float* ln1_g = (const float*)d_in[6];
    const float* ln1_b = (const float*)d_in[7];
    const float* qkv_w = (const float*)d_in[8];
    const float* out_w = (const float*)d_in[9];
    const float* out_b = (const float*)d_in[10];
    const float* ew1   = (const float*)d_in[11];
    const float* eb1   = (const float*)d_in[12];
    const float* ew2   = (const float*)d_in[13];
    const float* eb2   = (const float*)d_in[14];
    const float* cw1   = (const float*)d_in[15];
    const float* cb1   = (const float*)d_in[16];
    const float* cw2   = (const float*)d_in[17];
    const float* cb2   = (const float*)d_in[18];
    const float* c_scale = (const float*)d_in[19];
    const float* c_comb  = (const float*)d_in[20];
    const float* ln2_g = (const float*)d_in[21];
    const float* ln2_b = (const float*)d_in[22];
    const float* fw1   = (const float*)d_in[23];
    const float* fb1   = (const float*)d_in[24];
    const float* fw2   = (const float*)d_in[25];
    const float* fb2   = (const float*)d_in[26];
    const float* cls_w = (const float*)d_in[27];
    const float* cls_b = (const float*)d_in[28];

    float* ws   = (float*)d_ws;
    float* h    = ws;                       // 1024*64
    float* cA   = h + BN*DIM;               // 1024*3
    float* cB   = cA + BN*3;                // 1024*3
    float* qkv  = cB + BN*3;                // 1024*3072 (f32, ~12 MB)
    int*   idx  = (int*)(qkv + (size_t)BN*3*INNER); // 1024*30

    k_embed<<<BN, 64, 0, stream>>>(feats, coors, fe_w, fe_b, h, cA);

    float* cin = cA; float* cout = cB;
    for (int l = 0; l < 8; l++){
        k_qkv<<<16*24, 256, 0, stream>>>(h, ln1_g + l*DIM, ln1_b + l*DIM,
                                         qkv_w + (size_t)l*DIM*3*INNER, qkv);
        k_topk<<<BN/4, 256, 0, stream>>>(cin, idx);
        k_attn<<<BN, 256, 0, stream>>>(qkv, idx, cin, cout, edges, h,
                                       ew1 + l*9*18,  eb1 + l*18,
                                       ew2 + l*18*8,  eb2 + l*8,
                                       cw1 + l*8*64,  cb1 + l*64,
                                       cw2 + l*64*8,  cb2 + l*8,
                                       c_scale + l,   c_comb + l*8,
                                       out_w + (size_t)l*INNER*DIM, out_b + l*DIM);
        k_ffn<<<BN, 256, 0, stream>>>(h, ln2_g + l*DIM, ln2_b + l*DIM,
                                      fw1 + (size_t)l*DIM*256, fb1 + l*256,
                                      fw2 + (size_t)l*256*DIM, fb2 + l*64);
        float* tmp = cin; cin = cout; cout = tmp;
    }

    k_cls<<<BN, 64, 0, stream>>>(h, cls_w, cls_b, (float*)d_out);
}